// Round 16
// baseline (652.079 us; speedup 1.0000x reference)
//
#include <hip/hip_runtime.h>
#include <stdint.h>

typedef unsigned int u32;
typedef unsigned long long u64;
typedef int v4i __attribute__((ext_vector_type(4)));
typedef int v16i __attribute__((ext_vector_type(16)));

// ---------------------------------------------------------------------------
// Threefry-2x32, 20 rounds — bit-exact replica of JAX's threefry2x32 primitive.
// ---------------------------------------------------------------------------
__host__ __device__ __forceinline__ void tf2x32(u32 k0, u32 k1, u32 x0, u32 x1,
                                                u32& o0, u32& o1) {
  u32 k2 = k0 ^ k1 ^ 0x1BD11BDAu;
  x0 += k0; x1 += k1;
#ifdef __HIP_DEVICE_COMPILE__
#define ROTL(v, r) __builtin_rotateleft32((v), (r))
#else
#define ROTL(v, r) (((v) << (r)) | ((v) >> (32 - (r))))
#endif
#define TFR(r) { x0 += x1; x1 = ROTL(x1, r); x1 ^= x0; }
  TFR(13) TFR(15) TFR(26) TFR(6)   x0 += k1; x1 += k2 + 1u;
  TFR(17) TFR(29) TFR(16) TFR(24)  x0 += k2; x1 += k0 + 2u;
  TFR(13) TFR(15) TFR(26) TFR(6)   x0 += k0; x1 += k1 + 3u;
  TFR(17) TFR(29) TFR(16) TFR(24)  x0 += k1; x1 += k2 + 4u;
  TFR(13) TFR(15) TFR(26) TFR(6)   x0 += k2; x1 += k0 + 5u;
#undef TFR
#undef ROTL
  o0 = x0; o1 = x1;
}

// stoch_act decision, clip-free (exact; see r13): out = -1 iff !(2u < y+1).
__device__ __forceinline__ bool act_neg(float y, u32 k0, u32 k1, u32 j) {
  u32 o0, o1;
  tf2x32(k0, k1, 0u, j, o0, o1);
  u32 bits = o0 ^ o1;
  float uf = __uint_as_float(0x3f800000u | (bits >> 9));
  float u2 = __builtin_fmaf(uf, 2.0f, -2.0f);
  float t1 = y + 1.0f;
  return !(u2 < t1);
}

// ---------------------------------------------------------------------------
// Conv weight pack directly into i8 MFMA B-fragment order.
// bf[((cot*W + kt)*9 + t)*256 + l*4 + i4], bytes b:
//   co = cot*32 + (l&31), ci = kt*32 + (l>>5)*16 + i4*4 + b, tap t.
// i8 = +1 if w>=0 else -1 (0x01 / 0xFF).
// ---------------------------------------------------------------------------
__global__ void k_pack_wfrag(const float* __restrict__ w, u32* __restrict__ bf,
                             int Cout, int Cin) {
  const int W = Cin >> 5;
  const int total = (Cout >> 5) * W * 9 * 256;
  int idx = blockIdx.x * blockDim.x + threadIdx.x;
  if (idx >= total) return;
  int i4 = idx & 3;
  int l = (idx >> 2) & 63;
  int t = (idx >> 8) % 9;
  int kt = (idx / 2304) % W;
  int cot = idx / (2304 * W);
  int co = cot * 32 + (l & 31);
  int ci0 = kt * 32 + (l >> 5) * 16 + i4 * 4;
  int kh = t / 3, kw = t % 3;
  u32 v = 0;
#pragma unroll
  for (int b = 0; b < 4; ++b) {
    float wf = w[((size_t)(co * Cin + ci0 + b) * 3 + kh) * 3 + kw];
    v |= (wf < 0.0f ? 0xFFu : 0x01u) << (8 * b);
  }
  bf[idx] = v;
}

// FC1 weight pack into i8 MFMA B-fragment order:
// bfc[(ot*256 + kt)*256 + l*4 + q], byte b: o = ot*32+(l&31),
// k = kt*32 + (l>>5)*16 + q*4 + b. (O=1024, K=8192.)
__global__ void k_pack_fcbf(const float* __restrict__ w, u32* __restrict__ bfc) {
  int idx = blockIdx.x * blockDim.x + threadIdx.x;
  if (idx >= 32 * 256 * 256) return;
  int q = idx & 3;
  int l = (idx >> 2) & 63;
  int kt = (idx >> 8) & 255;
  int ot = idx >> 16;
  int o = ot * 32 + (l & 31);
  int k0i = kt * 32 + (l >> 5) * 16 + q * 4;
  u32 v = 0;
#pragma unroll
  for (int b = 0; b < 4; ++b) {
    float wf = w[(size_t)o * 8192 + k0i + b];
    v |= (wf < 0.0f ? 0xFFu : 0x01u) << (8 * b);
  }
  bfc[idx] = v;
}

// FC weight pack, transposed for coalesced lane=o loads: pwT[k4][o][j].
__global__ void k_pack_fcwT(const float* __restrict__ w, u32* __restrict__ pwT,
                            int O, int K) {
  int KW = K >> 5;
  int idx = blockIdx.x * blockDim.x + threadIdx.x;
  if (idx >= O * KW) return;
  int kw = idx % KW, o = idx / KW;
  const float4* src = (const float4*)(w + (size_t)o * K + kw * 32);
  u32 word = 0;
#pragma unroll
  for (int b4 = 0; b4 < 8; ++b4) {
    float4 f = src[b4];
    word |= (f.x < 0.0f ? 1u : 0u) << (b4 * 4 + 0);
    word |= (f.y < 0.0f ? 1u : 0u) << (b4 * 4 + 1);
    word |= (f.z < 0.0f ? 1u : 0u) << (b4 * 4 + 2);
    word |= (f.w < 0.0f ? 1u : 0u) << (b4 * 4 + 3);
  }
  int k4 = kw >> 2, j = kw & 3;
  pwT[((size_t)k4 * O + o) * 4 + j] = word;
}

// FC weight pack, row-major (fc3).
__global__ void k_pack_fcw(const float* __restrict__ w, u32* __restrict__ pw,
                           int O, int K) {
  int KW = K >> 5;
  int idx = blockIdx.x * blockDim.x + threadIdx.x;
  if (idx >= O * KW) return;
  int kw = idx % KW, o = idx / KW;
  const float4* src = (const float4*)(w + (size_t)o * K + kw * 32);
  u32 word = 0;
#pragma unroll
  for (int b4 = 0; b4 < 8; ++b4) {
    float4 f = src[b4];
    word |= (f.x < 0.0f ? 1u : 0u) << (b4 * 4 + 0);
    word |= (f.y < 0.0f ? 1u : 0u) << (b4 * 4 + 1);
    word |= (f.z < 0.0f ? 1u : 0u) << (b4 * 4 + 2);
    word |= (f.w < 0.0f ? 1u : 0u) << (b4 * 4 + 3);
  }
  pw[idx] = word;
}

// ---------------------------------------------------------------------------
// conv1: fp32 x [64][3][32][32], binarized w1, +b1, stoch_act key0.
// Output PLANAR packed: a1[(n*4 + w)*1024 + y*32 + x]. One wave per (n,y,x).
// ---------------------------------------------------------------------------
__global__ __launch_bounds__(256) void k_conv1(
    const float* __restrict__ x, const float* __restrict__ w1,
    const float* __restrict__ b1, u32 k0, u32 k1, u32* __restrict__ out) {
  int wave = (blockIdx.x * 256 + threadIdx.x) >> 6;
  int lane = threadIdx.x & 63;
  int n = wave >> 10;
  int rem = wave & 1023;
  int y = rem >> 5, xx = rem & 31;

  float xv[27];
#pragma unroll
  for (int ci = 0; ci < 3; ++ci)
#pragma unroll
    for (int dy = -1; dy <= 1; ++dy)
#pragma unroll
      for (int dx = -1; dx <= 1; ++dx) {
        int gy = y + dy, gx = xx + dx;
        float v = 0.0f;
        if ((unsigned)gy < 32u && (unsigned)gx < 32u)
          v = x[((n * 3 + ci) * 32 + gy) * 32 + gx];
        xv[(ci * 3 + (dy + 1)) * 3 + (dx + 1)] = v;
      }

  u64 bm[2];
#pragma unroll
  for (int h = 0; h < 2; ++h) {
    int co = lane + h * 64;
    float acc = 0.0f;
#pragma unroll
    for (int kh = 0; kh < 3; ++kh)
#pragma unroll
      for (int kw = 0; kw < 3; ++kw)
#pragma unroll
        for (int ci = 0; ci < 3; ++ci) {
          int k = (ci * 3 + kh) * 3 + kw;
          float wv = w1[co * 27 + k];
          acc += (wv < 0.0f) ? -xv[k] : xv[k];
        }
    float yv = acc + b1[co];
    u32 j = ((u32)(n * 128 + co) << 10) | (u32)(y << 5) | (u32)xx;
    bm[h] = __ballot(act_neg(yv, k0, k1, j));
  }
  if (lane < 4) {
    u32 wsel = (lane & 1) ? (u32)(bm[lane >> 1] >> 32) : (u32)bm[lane >> 1];
    out[(u32)(n * 4 + lane) * 1024u + (u32)(y * 32 + xx)] = wsel;
  }
}

// ---------------------------------------------------------------------------
// Binary conv via i8 MFMA (layers 2..6), v13 — r15-proven dataflow; NW waves
// per block share one staged slice (NW=8 for Cout=256, NW=16 for Cout=512
// with z=1 so the input expand is done once instead of twice).
// ---------------------------------------------------------------------------
template <int W, int NW>
__global__ __launch_bounds__(NW * 64) void k_bconv12(
    const u32* __restrict__ in, const u32* __restrict__ bfrag,
    const float* __restrict__ bias, int Cout, u32 k0, u32 k1,
    u32* __restrict__ out) {
  const int tid = threadIdx.x;
  const int lane = tid & 63;
  const int wv = tid >> 6;
  const int n = blockIdx.x;
  const int y0 = blockIdx.y * 4;
  const int cot = blockIdx.z * NW + wv;
  const int WOUT = Cout >> 5;

  __shared__ __align__(16) u32 sl[2][2][6 * 36 * 4];

  // Expand-item geometry: item = (row r, x col xc); 204 active threads.
  const int er = tid / 34;
  const int exc = tid % 34;
  const bool eact = tid < 204;
  const int egy = y0 - 1 + er;
  const int egx = exc - 1;
  const bool ein =
      eact && ((unsigned)egy < 32u) && ((unsigned)egx < 32u);

  v16i acc[4];
#pragma unroll
  for (int r = 0; r < 4; ++r)
#pragma unroll
    for (int e = 0; e < 16; ++e) acc[r][e] = 0;

  // Prologue: stage slice 0 (OOB cells = true i8 zero), b128 writes.
  {
    u32 word = ein ? in[(u32)(n * W) * 1024u + (u32)(egy * 32 + egx)] : 0u;
    if (eact) {
#pragma unroll
      for (int h = 0; h < 2; ++h) {
        v4i v;
#pragma unroll
        for (int q = 0; q < 4; ++q) {
          u32 nib = (word >> ((4 * h + q) * 4)) & 0xFu;
          u32 spread = (nib * 0x00204081u) & 0x01010101u;
          u32 val = (spread * 0xFEu) ^ 0x01010101u;
          v[q] = ein ? (int)val : 0;
        }
        *(v4i*)&sl[0][h][(er * 36 + exc) * 4] = v;
      }
    }
  }
  __syncthreads();

#pragma unroll 1
  for (int kt = 0; kt < W; ++kt) {
    const int cur = kt & 1;
    // Early-issue next slice's global load (hides under af reads + MFMA).
    u32 wn = 0;
    if (kt + 1 < W && ein)
      wn = in[(u32)(n * W + kt + 1) * 1024u + (u32)(egy * 32 + egx)];

    // Load the 18 distinct A-fragments as aligned b128 reads.
    v4i af[18];
    const int xb = lane & 31;
    const u32* slc = sl[cur][lane >> 5];
#pragma unroll
    for (int sr = 0; sr < 6; ++sr)
#pragma unroll
      for (int dxx = 0; dxx < 3; ++dxx)
        af[sr * 3 + dxx] = *(const v4i*)&slc[(sr * 36 + xb + dxx) * 4];

    const u32* bptr = bfrag + ((size_t)(cot * W + kt) * 9) * 256 + lane * 4;
#pragma unroll
    for (int t = 0; t < 9; ++t) {
      v4i B = *(const v4i*)(bptr + t * 256);
      const int dy = t / 3 - 1, dxx = t % 3;
#pragma unroll
      for (int r = 0; r < 4; ++r)
        acc[r] = __builtin_amdgcn_mfma_i32_32x32x32_i8(
            af[(r + dy + 1) * 3 + dxx], B, acc[r], 0, 0, 0);
    }

    // Expand-write next slice (OOB cells = true i8 zero), b128 writes.
    if (kt + 1 < W && eact) {
#pragma unroll
      for (int h = 0; h < 2; ++h) {
        v4i v;
#pragma unroll
        for (int q = 0; q < 4; ++q) {
          u32 nib = (wn >> ((4 * h + q) * 4)) & 0xFu;
          u32 spread = (nib * 0x00204081u) & 0x01010101u;
          u32 val = (spread * 0xFEu) ^ 0x01010101u;
          v[q] = ein ? (int)val : 0;
        }
        *(v4i*)&sl[cur ^ 1][h][(er * 36 + exc) * 4] = v;
      }
    }
    __syncthreads();
  }

  // Epilogue: bias + stoch_act + ballot-pack into planar channel words.
  const int co = cot * 32 + (lane & 31);
  const float bo = bias[co];
  const u32 jb = (u32)(n * Cout + co) * 1024u;
  const u32 obase = (u32)(n * WOUT + cot) * 1024u;
#pragma unroll
  for (int r = 0; r < 4; ++r) {
    const int y = y0 + r;
#pragma unroll
    for (int reg = 0; reg < 16; ++reg) {
      const int mlo = (reg & 3) + 8 * (reg >> 2);
      const int m = mlo + 4 * (lane >> 5);
      float yv = (float)acc[r][reg] + bo;
      bool neg = act_neg(yv, k0, k1, jb + (u32)(y * 32 + m));
      u64 b = __ballot(neg);
      if ((lane & 31) == 0) {
        u32 vsel = (lane == 0) ? (u32)b : (u32)(b >> 32);
        out[obase + (u32)(y * 32 + mlo + (lane >> 5) * 4)] = vsel;
      }
    }
  }
}

// ---------------------------------------------------------------------------
// Repack conv6 PLANAR output into FC1 row layout (x-packed).
// ---------------------------------------------------------------------------
__global__ void k_repack(const u32* __restrict__ a6, u32* __restrict__ f0) {
  int idx = blockIdx.x * blockDim.x + threadIdx.x;
  if (idx >= 4096 * 256) return;
  int w = idx & 255, r = idx >> 8;
  int n = r >> 6, chi = r & 63;
  int clo = w >> 5, yy = w & 31;
  int c = chi * 8 + clo;
  const u32* base = a6 + (u32)(n * 16 + (c >> 5)) * 1024u + (u32)(yy * 32);
  u32 sh = (u32)(c & 31);
  u32 word = 0;
#pragma unroll
  for (int xp = 0; xp < 32; ++xp)
    word |= ((base[xp] >> sh) & 1u) << xp;
  f0[idx] = word;
}

// ---------------------------------------------------------------------------
// FC1 via i8 MFMA: M=4096 rows, N=1024 outs, K=8192. Block = 512 thr =
// 8 waves; block tile = 32 rows x 256 outs (wave wv owns out-tile
// ot = blockIdx.y*8+wv). K-chunks of 256: A-chunk (32 rows x 256 i8 = 8KB)
// expanded into double-buffered LDS (same expand/barrier pattern as bconv);
// B from the fragment-ordered global buffer. Epilogue = proven k_fct
// semantics (j = r*1024 + o), ballot-packed to f1[r][ot].
// ---------------------------------------------------------------------------
__global__ __launch_bounds__(512) void k_fcm(
    const u32* __restrict__ f0, const u32* __restrict__ bfc,
    const float* __restrict__ bias, u32 k0, u32 k1, u32* __restrict__ out) {
  const int tid = threadIdx.x;
  const int lane = tid & 63;
  const int wv = tid >> 6;
  const int rbase = blockIdx.x * 32;
  const int ot = blockIdx.y * 8 + wv;
  const int obase = ot * 32;

  __shared__ __align__(16) u32 sl[2][8][2][32 * 4];  // [buf][kt8][half][row*4+q]

  const int ikt = tid >> 5;   // 0..7 for tid<256
  const int irow = tid & 31;
  const bool eact = tid < 256;

  v16i acc;
#pragma unroll
  for (int e = 0; e < 16; ++e) acc[e] = 0;

  // Prologue: stage chunk 0.
  if (eact) {
    u32 word = f0[(u32)(rbase + irow) * 256u + (u32)ikt];
#pragma unroll
    for (int h = 0; h < 2; ++h) {
      v4i v;
#pragma unroll
      for (int q = 0; q < 4; ++q) {
        u32 nib = (word >> ((4 * h + q) * 4)) & 0xFu;
        u32 spread = (nib * 0x00204081u) & 0x01010101u;
        v[q] = (int)((spread * 0xFEu) ^ 0x01010101u);
      }
      *(v4i*)&sl[0][ikt][h][irow * 4] = v;
    }
  }
  __syncthreads();

#pragma unroll 1
  for (int ch = 0; ch < 32; ++ch) {
    const int cur = ch & 1;
    u32 wn = 0;
    if (ch + 1 < 32 && eact)
      wn = f0[(u32)(rbase + irow) * 256u + (u32)((ch + 1) * 8 + ikt)];

    const u32* bptr = bfc + ((size_t)(ot * 256 + ch * 8)) * 256 + lane * 4;
#pragma unroll
    for (int k8 = 0; k8 < 8; ++k8) {
      v4i A = *(const v4i*)&sl[cur][k8][lane >> 5][(lane & 31) * 4];
      v4i B = *(const v4i*)(bptr + k8 * 256);
      acc = __builtin_amdgcn_mfma_i32_32x32x32_i8(A, B, acc, 0, 0, 0);
    }

    if (ch + 1 < 32 && eact) {
#pragma unroll
      for (int h = 0; h < 2; ++h) {
        v4i v;
#pragma unroll
        for (int q = 0; q < 4; ++q) {
          u32 nib = (wn >> ((4 * h + q) * 4)) & 0xFu;
          u32 spread = (nib * 0x00204081u) & 0x01010101u;
          v[q] = (int)((spread * 0xFEu) ^ 0x01010101u);
        }
        *(v4i*)&sl[cur ^ 1][ikt][h][irow * 4] = v;
      }
    }
    __syncthreads();
  }

  // Epilogue: bias + stoch_act (j = r*1024 + o) + ballot-pack to f1[r][ot].
  const int o = obase + (lane & 31);
  const float bo = bias[o];
#pragma unroll
  for (int reg = 0; reg < 16; ++reg) {
    const int rlo = (reg & 3) + 8 * (reg >> 2);
    const int r = rbase + rlo + 4 * (lane >> 5);
    float yv = (float)acc[reg] + bo;
    bool neg = act_neg(yv, k0, k1, (u32)r * 1024u + (u32)o);
    u64 b = __ballot(neg);
    if ((lane & 31) == 0) {
      u32 vsel = (lane == 0) ? (u32)b : (u32)(b >> 32);
      int rw = rbase + rlo + (lane >> 5) * 4;
      out[(size_t)rw * 32 + (u32)ot] = vsel;
    }
  }
}

// ---------------------------------------------------------------------------
// Binary FC with transposed weights (proven round 4) — used for FC2.
// ---------------------------------------------------------------------------
template <int KW>
__global__ __launch_bounds__(256, 4) void k_fct(
    const u32* __restrict__ in, const u32* __restrict__ pwT,
    const float* __restrict__ bias, int O, u32 k0, u32 k1,
    u32* __restrict__ out) {
  const int tid = threadIdx.x, lane = tid & 63;
  const int wv = __builtin_amdgcn_readfirstlane(tid >> 6);
  const int rbase = blockIdx.x * 32;
  const int obase = blockIdx.y * 64;
  __shared__ __align__(16) u32 rows[32 * KW];
  for (int i = tid; i < 32 * KW; i += 256)
    rows[i] = in[(size_t)(rbase + i / KW) * KW + (i % KW)];
  __syncthreads();

  const int o = obase + lane;
  const int r0 = wv * 8;
  u32 acc[8];
#pragma unroll
  for (int rr = 0; rr < 8; ++rr) acc[rr] = 0;
  for (int k4 = 0; k4 < KW / 4; ++k4) {
    uint4 w4 = ((const uint4*)pwT)[(size_t)k4 * O + o];
#pragma unroll
    for (int rr = 0; rr < 8; ++rr) {
      uint4 av = *(const uint4*)&rows[(r0 + rr) * KW + k4 * 4];
      acc[rr] += __popc(av.x ^ w4.x) + __popc(av.y ^ w4.y) +
                 __popc(av.z ^ w4.z) + __popc(av.w ^ w4.w);
    }
  }
  const int OW = O >> 5;
  const float bo = bias[o];
#pragma unroll
  for (int rr = 0; rr < 8; ++rr) {
    int r = rbase + r0 + rr;
    float yv = (float)(KW * 32 - 2 * (int)acc[rr]) + bo;
    bool neg = act_neg(yv, k0, k1, (u32)r * (u32)O + (u32)o);
    u64 b = __ballot(neg);
    if (lane == 0) {
      out[(size_t)r * OW + (obase >> 5)] = (u32)b;
      out[(size_t)r * OW + (obase >> 5) + 1] = (u32)(b >> 32);
    }
  }
}

// FC3: [4096][32 words] x [10][32 words] -> fp32 +-1 output [4096][10].
__global__ __launch_bounds__(64) void k_fc3(
    const u32* __restrict__ in, const u32* __restrict__ pw,
    const float* __restrict__ bias, u32 k0, u32 k1,
    float* __restrict__ outp) {
  const int lane = threadIdx.x;
  const int r = blockIdx.x;
  __shared__ u32 row[32];
  if (lane < 32) row[lane] = in[(size_t)r * 32 + lane];
  __syncthreads();
  if (lane < 10) {
    int acc = 0;
#pragma unroll
    for (int k = 0; k < 32; ++k) acc += __popc(row[k] ^ pw[lane * 32 + k]);
    float yv = (float)(1024 - 2 * acc) + bias[lane];
    bool neg = act_neg(yv, k0, k1, (u32)r * 10u + (u32)lane);
    outp[(size_t)r * 10 + lane] = neg ? -1.0f : 1.0f;
  }
}

// ---------------------------------------------------------------------------
extern "C" void kernel_launch(void* const* d_in, const int* in_sizes, int n_in,
                              void* d_out, int out_size, void* d_ws,
                              size_t ws_size, hipStream_t stream) {
  const float* x   = (const float*)d_in[0];
  const float* w1  = (const float*)d_in[1];
  const float* b1  = (const float*)d_in[2];
  const float* w2  = (const float*)d_in[3];
  const float* b2  = (const float*)d_in[4];
  const float* w3  = (const float*)d_in[5];
  const float* b3  = (const float*)d_in[6];
  const float* w4  = (const float*)d_in[7];
  const float* b4  = (const float*)d_in[8];
  const float* w5  = (const float*)d_in[9];
  const float* b5  = (const float*)d_in[10];
  const float* w6  = (const float*)d_in[11];
  const float* b6  = (const float*)d_in[12];
  const float* fw1 = (const float*)d_in[13];
  const float* fb1 = (const float*)d_in[14];
  const float* fw2 = (const float*)d_in[15];
  const float* fb2 = (const float*)d_in[16];
  const float* fw3 = (const float*)d_in[17];
  const float* fb3 = (const float*)d_in[18];

  u32 K[9][2];
  for (int i = 0; i < 9; ++i) tf2x32(0u, 42u, 0u, (u32)i, K[i][0], K[i][1]);

  char* ws = (char*)d_ws;
  size_t off = 0;
  auto alloc = [&](size_t bytes) -> char* {
    char* p = ws + off;
    off += (bytes + 255) & ~(size_t)255;
    return p;
  };
  // i8 MFMA weight fragment buffers: Cout*9*Cin bytes each.
  u32* bf2  = (u32*)alloc(256u * 9 * 128);
  u32* bf3  = (u32*)alloc(256u * 9 * 256);
  u32* bf4  = (u32*)alloc(256u * 9 * 256);
  u32* bf5  = (u32*)alloc(512u * 9 * 256);
  u32* bf6  = (u32*)alloc(512u * 9 * 512);
  u32* bfc1 = (u32*)alloc(1024u * 8192);      // FC1 B-fragments, 8 MB
  u32* pfw2 = (u32*)alloc(1024u * 32 * 4);
  u32* pfw3 = (u32*)alloc(10u * 32 * 4);
  u32* a1   = (u32*)alloc(64u * 1024 * 4 * 4);
  u32* a2   = (u32*)alloc(64u * 1024 * 8 * 4);
  u32* a3   = (u32*)alloc(64u * 1024 * 8 * 4);
  u32* a4   = (u32*)alloc(64u * 1024 * 8 * 4);
  u32* a5   = (u32*)alloc(64u * 1024 * 16 * 4);
  u32* a6   = (u32*)alloc(64u * 1024 * 16 * 4);
  u32* f0   = (u32*)alloc(4096u * 256 * 4);
  u32* f1   = (u32*)alloc(4096u * 32 * 4);
  u32* f2   = (u32*)alloc(4096u * 32 * 4);
  (void)ws_size;  // ~34 MB of workspace

  int t;
  t = (256 / 32) * 4 * 9 * 256;
  k_pack_wfrag<<<(t + 255) / 256, 256, 0, stream>>>(w2, bf2, 256, 128);
  t = (256 / 32) * 8 * 9 * 256;
  k_pack_wfrag<<<(t + 255) / 256, 256, 0, stream>>>(w3, bf3, 256, 256);
  k_pack_wfrag<<<(t + 255) / 256, 256, 0, stream>>>(w4, bf4, 256, 256);
  t = (512 / 32) * 8 * 9 * 256;
  k_pack_wfrag<<<(t + 255) / 256, 256, 0, stream>>>(w5, bf5, 512, 256);
  t = (512 / 32) * 16 * 9 * 256;
  k_pack_wfrag<<<(t + 255) / 256, 256, 0, stream>>>(w6, bf6, 512, 512);
  t = 32 * 256 * 256;
  k_pack_fcbf<<<(t + 255) / 256, 256, 0, stream>>>(fw1, bfc1);
  t = 1024 * 32;
  k_pack_fcwT<<<(t + 255) / 256, 256, 0, stream>>>(fw2, pfw2, 1024, 1024);
  t = 10 * 32;
  k_pack_fcw<<<(t + 255) / 256, 256, 0, stream>>>(fw3, pfw3, 10, 1024);

  k_conv1<<<16384, 256, 0, stream>>>(x, w1, b1, K[0][0], K[0][1], a1);
  k_bconv12<4, 8><<<dim3(64, 8, 1), 512, 0, stream>>>(a1, bf2, b2, 256,
                                                      K[1][0], K[1][1], a2);
  k_bconv12<8, 8><<<dim3(64, 8, 1), 512, 0, stream>>>(a2, bf3, b3, 256,
                                                      K[2][0], K[2][1], a3);
  k_bconv12<8, 8><<<dim3(64, 8, 1), 512, 0, stream>>>(a3, bf4, b4, 256,
                                                      K[3][0], K[3][1], a4);
  k_bconv12<8, 16><<<dim3(64, 8, 1), 1024, 0, stream>>>(a4, bf5, b5, 512,
                                                        K[4][0], K[4][1], a5);
  k_bconv12<16, 16><<<dim3(64, 8, 1), 1024, 0, stream>>>(a5, bf6, b6, 512,
                                                         K[5][0], K[5][1], a6);
  k_repack<<<(4096 * 256 + 255) / 256, 256, 0, stream>>>(a6, f0);
  k_fcm<<<dim3(128, 4), 512, 0, stream>>>(f0, bfc1, fb1, K[6][0], K[6][1], f1);
  k_fct<32><<<dim3(128, 16), 256, 0, stream>>>(f1, pfw2, fb2, 1024,
                                               K[7][0], K[7][1], f2);
  k_fc3<<<4096, 64, 0, stream>>>(f2, pfw3, fb3, K[8][0], K[8][1],
                                 (float*)d_out);
}

// Round 17
// 620.118 us; speedup vs baseline: 1.0515x; 1.0515x over previous
//
#include <hip/hip_runtime.h>
#include <stdint.h>

typedef unsigned int u32;
typedef unsigned long long u64;
typedef int v4i __attribute__((ext_vector_type(4)));
typedef int v16i __attribute__((ext_vector_type(16)));

// ---------------------------------------------------------------------------
// Threefry-2x32, 20 rounds — bit-exact replica of JAX's threefry2x32 primitive.
// ---------------------------------------------------------------------------
__host__ __device__ __forceinline__ void tf2x32(u32 k0, u32 k1, u32 x0, u32 x1,
                                                u32& o0, u32& o1) {
  u32 k2 = k0 ^ k1 ^ 0x1BD11BDAu;
  x0 += k0; x1 += k1;
#ifdef __HIP_DEVICE_COMPILE__
#define ROTL(v, r) __builtin_rotateleft32((v), (r))
#else
#define ROTL(v, r) (((v) << (r)) | ((v) >> (32 - (r))))
#endif
#define TFR(r) { x0 += x1; x1 = ROTL(x1, r); x1 ^= x0; }
  TFR(13) TFR(15) TFR(26) TFR(6)   x0 += k1; x1 += k2 + 1u;
  TFR(17) TFR(29) TFR(16) TFR(24)  x0 += k2; x1 += k0 + 2u;
  TFR(13) TFR(15) TFR(26) TFR(6)   x0 += k0; x1 += k1 + 3u;
  TFR(17) TFR(29) TFR(16) TFR(24)  x0 += k1; x1 += k2 + 4u;
  TFR(13) TFR(15) TFR(26) TFR(6)   x0 += k2; x1 += k0 + 5u;
#undef TFR
#undef ROTL
  o0 = x0; o1 = x1;
}

// stoch_act decision, clip-free (exact; see r13): out = -1 iff !(2u < y+1).
__device__ __forceinline__ bool act_neg(float y, u32 k0, u32 k1, u32 j) {
  u32 o0, o1;
  tf2x32(k0, k1, 0u, j, o0, o1);
  u32 bits = o0 ^ o1;
  float uf = __uint_as_float(0x3f800000u | (bits >> 9));
  float u2 = __builtin_fmaf(uf, 2.0f, -2.0f);
  float t1 = y + 1.0f;
  return !(u2 < t1);
}

// ---------------------------------------------------------------------------
// Conv weight pack directly into i8 MFMA B-fragment order.
// bf[((cot*W + kt)*9 + t)*256 + l*4 + i4], bytes b:
//   co = cot*32 + (l&31), ci = kt*32 + (l>>5)*16 + i4*4 + b, tap t.
// i8 = +1 if w>=0 else -1 (0x01 / 0xFF).
// ---------------------------------------------------------------------------
__global__ void k_pack_wfrag(const float* __restrict__ w, u32* __restrict__ bf,
                             int Cout, int Cin) {
  const int W = Cin >> 5;
  const int total = (Cout >> 5) * W * 9 * 256;
  int idx = blockIdx.x * blockDim.x + threadIdx.x;
  if (idx >= total) return;
  int i4 = idx & 3;
  int l = (idx >> 2) & 63;
  int t = (idx >> 8) % 9;
  int kt = (idx / 2304) % W;
  int cot = idx / (2304 * W);
  int co = cot * 32 + (l & 31);
  int ci0 = kt * 32 + (l >> 5) * 16 + i4 * 4;
  int kh = t / 3, kw = t % 3;
  u32 v = 0;
#pragma unroll
  for (int b = 0; b < 4; ++b) {
    float wf = w[((size_t)(co * Cin + ci0 + b) * 3 + kh) * 3 + kw];
    v |= (wf < 0.0f ? 0xFFu : 0x01u) << (8 * b);
  }
  bf[idx] = v;
}

// FC1 weight pack into i8 MFMA B-fragment order:
// bfc[(ot*256 + kt)*256 + l*4 + q], byte b: o = ot*32+(l&31),
// k = kt*32 + (l>>5)*16 + q*4 + b. (O=1024, K=8192.)
__global__ void k_pack_fcbf(const float* __restrict__ w, u32* __restrict__ bfc) {
  int idx = blockIdx.x * blockDim.x + threadIdx.x;
  if (idx >= 32 * 256 * 256) return;
  int q = idx & 3;
  int l = (idx >> 2) & 63;
  int kt = (idx >> 8) & 255;
  int ot = idx >> 16;
  int o = ot * 32 + (l & 31);
  int k0i = kt * 32 + (l >> 5) * 16 + q * 4;
  u32 v = 0;
#pragma unroll
  for (int b = 0; b < 4; ++b) {
    float wf = w[(size_t)o * 8192 + k0i + b];
    v |= (wf < 0.0f ? 0xFFu : 0x01u) << (8 * b);
  }
  bfc[idx] = v;
}

// FC weight pack, transposed for coalesced lane=o loads: pwT[k4][o][j].
__global__ void k_pack_fcwT(const float* __restrict__ w, u32* __restrict__ pwT,
                            int O, int K) {
  int KW = K >> 5;
  int idx = blockIdx.x * blockDim.x + threadIdx.x;
  if (idx >= O * KW) return;
  int kw = idx % KW, o = idx / KW;
  const float4* src = (const float4*)(w + (size_t)o * K + kw * 32);
  u32 word = 0;
#pragma unroll
  for (int b4 = 0; b4 < 8; ++b4) {
    float4 f = src[b4];
    word |= (f.x < 0.0f ? 1u : 0u) << (b4 * 4 + 0);
    word |= (f.y < 0.0f ? 1u : 0u) << (b4 * 4 + 1);
    word |= (f.z < 0.0f ? 1u : 0u) << (b4 * 4 + 2);
    word |= (f.w < 0.0f ? 1u : 0u) << (b4 * 4 + 3);
  }
  int k4 = kw >> 2, j = kw & 3;
  pwT[((size_t)k4 * O + o) * 4 + j] = word;
}

// FC weight pack, row-major (fc3).
__global__ void k_pack_fcw(const float* __restrict__ w, u32* __restrict__ pw,
                           int O, int K) {
  int KW = K >> 5;
  int idx = blockIdx.x * blockDim.x + threadIdx.x;
  if (idx >= O * KW) return;
  int kw = idx % KW, o = idx / KW;
  const float4* src = (const float4*)(w + (size_t)o * K + kw * 32);
  u32 word = 0;
#pragma unroll
  for (int b4 = 0; b4 < 8; ++b4) {
    float4 f = src[b4];
    word |= (f.x < 0.0f ? 1u : 0u) << (b4 * 4 + 0);
    word |= (f.y < 0.0f ? 1u : 0u) << (b4 * 4 + 1);
    word |= (f.z < 0.0f ? 1u : 0u) << (b4 * 4 + 2);
    word |= (f.w < 0.0f ? 1u : 0u) << (b4 * 4 + 3);
  }
  pw[idx] = word;
}

// ---------------------------------------------------------------------------
// conv1: fp32 x [64][3][32][32], binarized w1, +b1, stoch_act key0.
// Output PLANAR packed: a1[(n*4 + w)*1024 + y*32 + x]. One wave per (n,y,x).
// ---------------------------------------------------------------------------
__global__ __launch_bounds__(256) void k_conv1(
    const float* __restrict__ x, const float* __restrict__ w1,
    const float* __restrict__ b1, u32 k0, u32 k1, u32* __restrict__ out) {
  int wave = (blockIdx.x * 256 + threadIdx.x) >> 6;
  int lane = threadIdx.x & 63;
  int n = wave >> 10;
  int rem = wave & 1023;
  int y = rem >> 5, xx = rem & 31;

  float xv[27];
#pragma unroll
  for (int ci = 0; ci < 3; ++ci)
#pragma unroll
    for (int dy = -1; dy <= 1; ++dy)
#pragma unroll
      for (int dx = -1; dx <= 1; ++dx) {
        int gy = y + dy, gx = xx + dx;
        float v = 0.0f;
        if ((unsigned)gy < 32u && (unsigned)gx < 32u)
          v = x[((n * 3 + ci) * 32 + gy) * 32 + gx];
        xv[(ci * 3 + (dy + 1)) * 3 + (dx + 1)] = v;
      }

  u64 bm[2];
#pragma unroll
  for (int h = 0; h < 2; ++h) {
    int co = lane + h * 64;
    float acc = 0.0f;
#pragma unroll
    for (int kh = 0; kh < 3; ++kh)
#pragma unroll
      for (int kw = 0; kw < 3; ++kw)
#pragma unroll
        for (int ci = 0; ci < 3; ++ci) {
          int k = (ci * 3 + kh) * 3 + kw;
          float wv = w1[co * 27 + k];
          acc += (wv < 0.0f) ? -xv[k] : xv[k];
        }
    float yv = acc + b1[co];
    u32 j = ((u32)(n * 128 + co) << 10) | (u32)(y << 5) | (u32)xx;
    bm[h] = __ballot(act_neg(yv, k0, k1, j));
  }
  if (lane < 4) {
    u32 wsel = (lane & 1) ? (u32)(bm[lane >> 1] >> 32) : (u32)bm[lane >> 1];
    out[(u32)(n * 4 + lane) * 1024u + (u32)(y * 32 + xx)] = wsel;
  }
}

// ---------------------------------------------------------------------------
// Binary conv via i8 MFMA (layers 2..6) — r15-proven structure: 512-thread
// blocks (8 waves) share one double-buffered staged slice; wave wv owns cout
// chunk blockIdx.z*8+wv.
// ---------------------------------------------------------------------------
template <int W>
__global__ __launch_bounds__(512) void k_bconv12(
    const u32* __restrict__ in, const u32* __restrict__ bfrag,
    const float* __restrict__ bias, int Cout, u32 k0, u32 k1,
    u32* __restrict__ out) {
  const int tid = threadIdx.x;
  const int lane = tid & 63;
  const int wv = tid >> 6;
  const int n = blockIdx.x;
  const int y0 = blockIdx.y * 4;
  const int cot = blockIdx.z * 8 + wv;
  const int WOUT = Cout >> 5;

  __shared__ __align__(16) u32 sl[2][2][6 * 36 * 4];

  // Expand-item geometry: item = (row r, x col xc); 204 active threads.
  const int er = tid / 34;
  const int exc = tid % 34;
  const bool eact = tid < 204;
  const int egy = y0 - 1 + er;
  const int egx = exc - 1;
  const bool ein =
      eact && ((unsigned)egy < 32u) && ((unsigned)egx < 32u);

  v16i acc[4];
#pragma unroll
  for (int r = 0; r < 4; ++r)
#pragma unroll
    for (int e = 0; e < 16; ++e) acc[r][e] = 0;

  // Prologue: stage slice 0 (OOB cells = true i8 zero), b128 writes.
  {
    u32 word = ein ? in[(u32)(n * W) * 1024u + (u32)(egy * 32 + egx)] : 0u;
    if (eact) {
#pragma unroll
      for (int h = 0; h < 2; ++h) {
        v4i v;
#pragma unroll
        for (int q = 0; q < 4; ++q) {
          u32 nib = (word >> ((4 * h + q) * 4)) & 0xFu;
          u32 spread = (nib * 0x00204081u) & 0x01010101u;
          u32 val = (spread * 0xFEu) ^ 0x01010101u;
          v[q] = ein ? (int)val : 0;
        }
        *(v4i*)&sl[0][h][(er * 36 + exc) * 4] = v;
      }
    }
  }
  __syncthreads();

#pragma unroll 1
  for (int kt = 0; kt < W; ++kt) {
    const int cur = kt & 1;
    // Early-issue next slice's global load (hides under af reads + MFMA).
    u32 wn = 0;
    if (kt + 1 < W && ein)
      wn = in[(u32)(n * W + kt + 1) * 1024u + (u32)(egy * 32 + egx)];

    // Load the 18 distinct A-fragments as aligned b128 reads.
    v4i af[18];
    const int xb = lane & 31;
    const u32* slc = sl[cur][lane >> 5];
#pragma unroll
    for (int sr = 0; sr < 6; ++sr)
#pragma unroll
      for (int dxx = 0; dxx < 3; ++dxx)
        af[sr * 3 + dxx] = *(const v4i*)&slc[(sr * 36 + xb + dxx) * 4];

    const u32* bptr = bfrag + ((size_t)(cot * W + kt) * 9) * 256 + lane * 4;
#pragma unroll
    for (int t = 0; t < 9; ++t) {
      v4i B = *(const v4i*)(bptr + t * 256);
      const int dy = t / 3 - 1, dxx = t % 3;
#pragma unroll
      for (int r = 0; r < 4; ++r)
        acc[r] = __builtin_amdgcn_mfma_i32_32x32x32_i8(
            af[(r + dy + 1) * 3 + dxx], B, acc[r], 0, 0, 0);
    }

    // Expand-write next slice (OOB cells = true i8 zero), b128 writes.
    if (kt + 1 < W && eact) {
#pragma unroll
      for (int h = 0; h < 2; ++h) {
        v4i v;
#pragma unroll
        for (int q = 0; q < 4; ++q) {
          u32 nib = (wn >> ((4 * h + q) * 4)) & 0xFu;
          u32 spread = (nib * 0x00204081u) & 0x01010101u;
          u32 val = (spread * 0xFEu) ^ 0x01010101u;
          v[q] = ein ? (int)val : 0;
        }
        *(v4i*)&sl[cur ^ 1][h][(er * 36 + exc) * 4] = v;
      }
    }
    __syncthreads();
  }

  // Epilogue: bias + stoch_act + ballot-pack into planar channel words.
  const int co = cot * 32 + (lane & 31);
  const float bo = bias[co];
  const u32 jb = (u32)(n * Cout + co) * 1024u;
  const u32 obase = (u32)(n * WOUT + cot) * 1024u;
#pragma unroll
  for (int r = 0; r < 4; ++r) {
    const int y = y0 + r;
#pragma unroll
    for (int reg = 0; reg < 16; ++reg) {
      const int mlo = (reg & 3) + 8 * (reg >> 2);
      const int m = mlo + 4 * (lane >> 5);
      float yv = (float)acc[r][reg] + bo;
      bool neg = act_neg(yv, k0, k1, jb + (u32)(y * 32 + m));
      u64 b = __ballot(neg);
      if ((lane & 31) == 0) {
        u32 vsel = (lane == 0) ? (u32)b : (u32)(b >> 32);
        out[obase + (u32)(y * 32 + mlo + (lane >> 5) * 4)] = vsel;
      }
    }
  }
}

// ---------------------------------------------------------------------------
// Repack conv6 PLANAR output into FC1 row layout (x-packed).
// ---------------------------------------------------------------------------
__global__ void k_repack(const u32* __restrict__ a6, u32* __restrict__ f0) {
  int idx = blockIdx.x * blockDim.x + threadIdx.x;
  if (idx >= 4096 * 256) return;
  int w = idx & 255, r = idx >> 8;
  int n = r >> 6, chi = r & 63;
  int clo = w >> 5, yy = w & 31;
  int c = chi * 8 + clo;
  const u32* base = a6 + (u32)(n * 16 + (c >> 5)) * 1024u + (u32)(yy * 32);
  u32 sh = (u32)(c & 31);
  u32 word = 0;
#pragma unroll
  for (int xp = 0; xp < 32; ++xp)
    word |= ((base[xp] >> sh) & 1u) << xp;
  f0[idx] = word;
}

// ---------------------------------------------------------------------------
// FC1 via i8 MFMA (r16-proven): M=4096, N=1024, K=8192. Block = 512 thr =
// 8 waves; block tile = 32 rows x 256 outs; K-chunks of 256 expanded into
// double-buffered LDS; B from fragment-ordered global buffer.
// ---------------------------------------------------------------------------
__global__ __launch_bounds__(512) void k_fcm(
    const u32* __restrict__ f0, const u32* __restrict__ bfc,
    const float* __restrict__ bias, u32 k0, u32 k1, u32* __restrict__ out) {
  const int tid = threadIdx.x;
  const int lane = tid & 63;
  const int wv = tid >> 6;
  const int rbase = blockIdx.x * 32;
  const int ot = blockIdx.y * 8 + wv;
  const int obase = ot * 32;

  __shared__ __align__(16) u32 sl[2][8][2][32 * 4];  // [buf][kt8][half][row*4+q]

  const int ikt = tid >> 5;   // 0..7 for tid<256
  const int irow = tid & 31;
  const bool eact = tid < 256;

  v16i acc;
#pragma unroll
  for (int e = 0; e < 16; ++e) acc[e] = 0;

  // Prologue: stage chunk 0.
  if (eact) {
    u32 word = f0[(u32)(rbase + irow) * 256u + (u32)ikt];
#pragma unroll
    for (int h = 0; h < 2; ++h) {
      v4i v;
#pragma unroll
      for (int q = 0; q < 4; ++q) {
        u32 nib = (word >> ((4 * h + q) * 4)) & 0xFu;
        u32 spread = (nib * 0x00204081u) & 0x01010101u;
        v[q] = (int)((spread * 0xFEu) ^ 0x01010101u);
      }
      *(v4i*)&sl[0][ikt][h][irow * 4] = v;
    }
  }
  __syncthreads();

#pragma unroll 1
  for (int ch = 0; ch < 32; ++ch) {
    const int cur = ch & 1;
    u32 wn = 0;
    if (ch + 1 < 32 && eact)
      wn = f0[(u32)(rbase + irow) * 256u + (u32)((ch + 1) * 8 + ikt)];

    const u32* bptr = bfc + ((size_t)(ot * 256 + ch * 8)) * 256 + lane * 4;
#pragma unroll
    for (int k8 = 0; k8 < 8; ++k8) {
      v4i A = *(const v4i*)&sl[cur][k8][lane >> 5][(lane & 31) * 4];
      v4i B = *(const v4i*)(bptr + k8 * 256);
      acc = __builtin_amdgcn_mfma_i32_32x32x32_i8(A, B, acc, 0, 0, 0);
    }

    if (ch + 1 < 32 && eact) {
#pragma unroll
      for (int h = 0; h < 2; ++h) {
        v4i v;
#pragma unroll
        for (int q = 0; q < 4; ++q) {
          u32 nib = (wn >> ((4 * h + q) * 4)) & 0xFu;
          u32 spread = (nib * 0x00204081u) & 0x01010101u;
          v[q] = (int)((spread * 0xFEu) ^ 0x01010101u);
        }
        *(v4i*)&sl[cur ^ 1][ikt][h][irow * 4] = v;
      }
    }
    __syncthreads();
  }

  // Epilogue: bias + stoch_act (j = r*1024 + o) + ballot-pack to f1[r][ot].
  const int o = obase + (lane & 31);
  const float bo = bias[o];
#pragma unroll
  for (int reg = 0; reg < 16; ++reg) {
    const int rlo = (reg & 3) + 8 * (reg >> 2);
    const int r = rbase + rlo + 4 * (lane >> 5);
    float yv = (float)acc[reg] + bo;
    bool neg = act_neg(yv, k0, k1, (u32)r * 1024u + (u32)o);
    u64 b = __ballot(neg);
    if ((lane & 31) == 0) {
      u32 vsel = (lane == 0) ? (u32)b : (u32)(b >> 32);
      int rw = rbase + rlo + (lane >> 5) * 4;
      out[(size_t)rw * 32 + (u32)ot] = vsel;
    }
  }
}

// ---------------------------------------------------------------------------
// Binary FC with transposed weights (proven round 4) — used for FC2.
// ---------------------------------------------------------------------------
template <int KW>
__global__ __launch_bounds__(256, 4) void k_fct(
    const u32* __restrict__ in, const u32* __restrict__ pwT,
    const float* __restrict__ bias, int O, u32 k0, u32 k1,
    u32* __restrict__ out) {
  const int tid = threadIdx.x, lane = tid & 63;
  const int wv = __builtin_amdgcn_readfirstlane(tid >> 6);
  const int rbase = blockIdx.x * 32;
  const int obase = blockIdx.y * 64;
  __shared__ __align__(16) u32 rows[32 * KW];
  for (int i = tid; i < 32 * KW; i += 256)
    rows[i] = in[(size_t)(rbase + i / KW) * KW + (i % KW)];
  __syncthreads();

  const int o = obase + lane;
  const int r0 = wv * 8;
  u32 acc[8];
#pragma unroll
  for (int rr = 0; rr < 8; ++rr) acc[rr] = 0;
  for (int k4 = 0; k4 < KW / 4; ++k4) {
    uint4 w4 = ((const uint4*)pwT)[(size_t)k4 * O + o];
#pragma unroll
    for (int rr = 0; rr < 8; ++rr) {
      uint4 av = *(const uint4*)&rows[(r0 + rr) * KW + k4 * 4];
      acc[rr] += __popc(av.x ^ w4.x) + __popc(av.y ^ w4.y) +
                 __popc(av.z ^ w4.z) + __popc(av.w ^ w4.w);
    }
  }
  const int OW = O >> 5;
  const float bo = bias[o];
#pragma unroll
  for (int rr = 0; rr < 8; ++rr) {
    int r = rbase + r0 + rr;
    float yv = (float)(KW * 32 - 2 * (int)acc[rr]) + bo;
    bool neg = act_neg(yv, k0, k1, (u32)r * (u32)O + (u32)o);
    u64 b = __ballot(neg);
    if (lane == 0) {
      out[(size_t)r * OW + (obase >> 5)] = (u32)b;
      out[(size_t)r * OW + (obase >> 5) + 1] = (u32)(b >> 32);
    }
  }
}

// FC3: [4096][32 words] x [10][32 words] -> fp32 +-1 output [4096][10].
__global__ __launch_bounds__(64) void k_fc3(
    const u32* __restrict__ in, const u32* __restrict__ pw,
    const float* __restrict__ bias, u32 k0, u32 k1,
    float* __restrict__ outp) {
  const int lane = threadIdx.x;
  const int r = blockIdx.x;
  __shared__ u32 row[32];
  if (lane < 32) row[lane] = in[(size_t)r * 32 + lane];
  __syncthreads();
  if (lane < 10) {
    int acc = 0;
#pragma unroll
    for (int k = 0; k < 32; ++k) acc += __popc(row[k] ^ pw[lane * 32 + k]);
    float yv = (float)(1024 - 2 * acc) + bias[lane];
    bool neg = act_neg(yv, k0, k1, (u32)r * 10u + (u32)lane);
    outp[(size_t)r * 10 + lane] = neg ? -1.0f : 1.0f;
  }
}

// ---------------------------------------------------------------------------
extern "C" void kernel_launch(void* const* d_in, const int* in_sizes, int n_in,
                              void* d_out, int out_size, void* d_ws,
                              size_t ws_size, hipStream_t stream) {
  const float* x   = (const float*)d_in[0];
  const float* w1  = (const float*)d_in[1];
  const float* b1  = (const float*)d_in[2];
  const float* w2  = (const float*)d_in[3];
  const float* b2  = (const float*)d_in[4];
  const float* w3  = (const float*)d_in[5];
  const float* b3  = (const float*)d_in[6];
  const float* w4  = (const float*)d_in[7];
  const float* b4  = (const float*)d_in[8];
  const float* w5  = (const float*)d_in[9];
  const float* b5  = (const float*)d_in[10];
  const float* w6  = (const float*)d_in[11];
  const float* b6  = (const float*)d_in[12];
  const float* fw1 = (const float*)d_in[13];
  const float* fb1 = (const float*)d_in[14];
  const float* fw2 = (const float*)d_in[15];
  const float* fb2 = (const float*)d_in[16];
  const float* fw3 = (const float*)d_in[17];
  const float* fb3 = (const float*)d_in[18];

  u32 K[9][2];
  for (int i = 0; i < 9; ++i) tf2x32(0u, 42u, 0u, (u32)i, K[i][0], K[i][1]);

  char* ws = (char*)d_ws;
  size_t off = 0;
  auto alloc = [&](size_t bytes) -> char* {
    char* p = ws + off;
    off += (bytes + 255) & ~(size_t)255;
    return p;
  };
  // i8 MFMA weight fragment buffers: Cout*9*Cin bytes each.
  u32* bf2  = (u32*)alloc(256u * 9 * 128);
  u32* bf3  = (u32*)alloc(256u * 9 * 256);
  u32* bf4  = (u32*)alloc(256u * 9 * 256);
  u32* bf5  = (u32*)alloc(512u * 9 * 256);
  u32* bf6  = (u32*)alloc(512u * 9 * 512);
  u32* bfc1 = (u32*)alloc(1024u * 8192);      // FC1 B-fragments, 8 MB
  u32* pfw2 = (u32*)alloc(1024u * 32 * 4);
  u32* pfw3 = (u32*)alloc(10u * 32 * 4);
  u32* a1   = (u32*)alloc(64u * 1024 * 4 * 4);
  u32* a2   = (u32*)alloc(64u * 1024 * 8 * 4);
  u32* a3   = (u32*)alloc(64u * 1024 * 8 * 4);
  u32* a4   = (u32*)alloc(64u * 1024 * 8 * 4);
  u32* a5   = (u32*)alloc(64u * 1024 * 16 * 4);
  u32* a6   = (u32*)alloc(64u * 1024 * 16 * 4);
  u32* f0   = (u32*)alloc(4096u * 256 * 4);
  u32* f1   = (u32*)alloc(4096u * 32 * 4);
  u32* f2   = (u32*)alloc(4096u * 32 * 4);
  (void)ws_size;  // ~34 MB of workspace

  int t;
  t = (256 / 32) * 4 * 9 * 256;
  k_pack_wfrag<<<(t + 255) / 256, 256, 0, stream>>>(w2, bf2, 256, 128);
  t = (256 / 32) * 8 * 9 * 256;
  k_pack_wfrag<<<(t + 255) / 256, 256, 0, stream>>>(w3, bf3, 256, 256);
  k_pack_wfrag<<<(t + 255) / 256, 256, 0, stream>>>(w4, bf4, 256, 256);
  t = (512 / 32) * 8 * 9 * 256;
  k_pack_wfrag<<<(t + 255) / 256, 256, 0, stream>>>(w5, bf5, 512, 256);
  t = (512 / 32) * 16 * 9 * 256;
  k_pack_wfrag<<<(t + 255) / 256, 256, 0, stream>>>(w6, bf6, 512, 512);
  t = 32 * 256 * 256;
  k_pack_fcbf<<<(t + 255) / 256, 256, 0, stream>>>(fw1, bfc1);
  t = 1024 * 32;
  k_pack_fcwT<<<(t + 255) / 256, 256, 0, stream>>>(fw2, pfw2, 1024, 1024);
  t = 10 * 32;
  k_pack_fcw<<<(t + 255) / 256, 256, 0, stream>>>(fw3, pfw3, 10, 1024);

  k_conv1<<<16384, 256, 0, stream>>>(x, w1, b1, K[0][0], K[0][1], a1);
  k_bconv12<4><<<dim3(64, 8, 1), 512, 0, stream>>>(a1, bf2, b2, 256,
                                                   K[1][0], K[1][1], a2);
  k_bconv12<8><<<dim3(64, 8, 1), 512, 0, stream>>>(a2, bf3, b3, 256,
                                                   K[2][0], K[2][1], a3);
  k_bconv12<8><<<dim3(64, 8, 1), 512, 0, stream>>>(a3, bf4, b4, 256,
                                                   K[3][0], K[3][1], a4);
  k_bconv12<8><<<dim3(64, 8, 2), 512, 0, stream>>>(a4, bf5, b5, 512,
                                                   K[4][0], K[4][1], a5);
  k_bconv12<16><<<dim3(64, 8, 2), 512, 0, stream>>>(a5, bf6, b6, 512,
                                                    K[5][0], K[5][1], a6);
  k_repack<<<(4096 * 256 + 255) / 256, 256, 0, stream>>>(a6, f0);
  k_fcm<<<dim3(128, 4), 512, 0, stream>>>(f0, bfc1, fb1, K[6][0], K[6][1], f1);
  k_fct<32><<<dim3(128, 16), 256, 0, stream>>>(f1, pfw2, fb2, 1024,
                                               K[7][0], K[7][1], f2);
  k_fc3<<<4096, 64, 0, stream>>>(f2, pfw3, fb3, K[8][0], K[8][1],
                                 (float*)d_out);
}